// Round 10
// baseline (1071.529 us; speedup 1.0000x reference)
//
#include <hip/hip_runtime.h>

#define D 128

// ---------------------------------------------------------------- preprocess

__global__ __launch_bounds__(256) void k_count(const int* __restrict__ dst,
                                               int* __restrict__ deg, int E) {
    int i = blockIdx.x * 256 + threadIdx.x;
    if (i < E) atomicAdd(&deg[dst[i]], 1);
}

// chunk = 1024 elems per block; write per-block sums
__global__ __launch_bounds__(256) void k_chunk_sum(const int* __restrict__ deg,
                                                   int* __restrict__ bsum, int n) {
    __shared__ int sdata[256];
    int base = blockIdx.x * 1024;
    int s = 0;
    for (int j = 0; j < 4; ++j) {
        int idx = base + j * 256 + threadIdx.x;
        if (idx < n) s += deg[idx];
    }
    sdata[threadIdx.x] = s;
    __syncthreads();
    for (int off = 128; off > 0; off >>= 1) {
        if (threadIdx.x < off) sdata[threadIdx.x] += sdata[threadIdx.x + off];
        __syncthreads();
    }
    if (threadIdx.x == 0) bsum[blockIdx.x] = sdata[0];
}

// serial exclusive scan of block sums (nb ~ 98, trivial)
__global__ void k_scan_bsums(int* bsum, int nb, int* offs, int n, int E) {
    if (threadIdx.x == 0 && blockIdx.x == 0) {
        int run = 0;
        for (int i = 0; i < nb; ++i) { int v = bsum[i]; bsum[i] = run; run += v; }
        offs[n] = E;
    }
}

// per-block local exclusive scan + base; also emit cursor copy and dinv
__global__ __launch_bounds__(256) void k_local_scan(const int* __restrict__ deg,
                                                    const int* __restrict__ bsum,
                                                    int* __restrict__ offs,
                                                    int* __restrict__ cursor,
                                                    float* __restrict__ dinv, int n) {
    __shared__ int tsum[256];
    int base = blockIdx.x * 1024;
    int v[4];
    int s = 0;
    for (int j = 0; j < 4; ++j) {
        int idx = base + threadIdx.x * 4 + j;
        v[j] = (idx < n) ? deg[idx] : 0;
        s += v[j];
    }
    tsum[threadIdx.x] = s;
    __syncthreads();
    for (int off = 1; off < 256; off <<= 1) {
        int t = (threadIdx.x >= (unsigned)off) ? tsum[threadIdx.x - off] : 0;
        __syncthreads();
        tsum[threadIdx.x] += t;
        __syncthreads();
    }
    int excl = tsum[threadIdx.x] - s;
    int run = bsum[blockIdx.x] + excl;
    for (int j = 0; j < 4; ++j) {
        int idx = base + threadIdx.x * 4 + j;
        if (idx < n) {
            offs[idx] = run;
            cursor[idx] = run;
            dinv[idx] = rsqrtf((float)v[j] + 1.0f);
            run += v[j];
        }
    }
}

__global__ __launch_bounds__(256) void k_fill(const int* __restrict__ src,
                                              const int* __restrict__ dst,
                                              const float* __restrict__ dinv,
                                              int* __restrict__ cursor,
                                              int2* __restrict__ csr, int E) {
    int i = blockIdx.x * 256 + threadIdx.x;
    if (i >= E) return;
    int s = src[i], d = dst[i];
    int p = atomicAdd(&cursor[d], 1);
    float w = dinv[s] * dinv[d];
    csr[p] = make_int2(s, __float_as_int(w));
}

// ---------------------------------------------------------------- GEMM  H[n,128] @ W[128,128]
// block: 256 threads, tile 256 rows. thread: 4 rows x 32 cols.
// Rationale (R6): LDS-throughput-bound at 2 rows/thread (32 ds_read_b128 per
// k4 per wave ~ 384 cyc vs 512 VALU, x8 waves/CU shared LDS). 4 rows amortizes
// each ds_read over 2x FMAs -> LDS floor ~31us, VALU ~21us per layer.
// acc = 4*8 float4 = 128 VGPR; fits 2 waves/SIMD (<=256).
__global__ __launch_bounds__(256, 2) void k_gemm(const float* __restrict__ H,
                                                 const float* __restrict__ W,
                                                 float* __restrict__ O, int nrows) {
    __shared__ float Wl[128 * 128];
    float4* Wl4 = (float4*)Wl;
    const float4* W4 = (const float4*)W;
    for (int i = threadIdx.x; i < 4096; i += 256) Wl4[i] = W4[i];
    __syncthreads();

    int tr = threadIdx.x >> 2;   // 0..63
    int cg = threadIdx.x & 3;    // col group; cols 4*(cg + 4*jj) .. +3
    long row0 = (long)blockIdx.x * 256 + tr * 4;
    if (row0 >= nrows) return;   // after the only barrier

    const float4* Hp[4];
    bool ok[4];
#pragma unroll
    for (int i = 0; i < 4; ++i) {
        long rr = row0 + i;
        ok[i] = rr < nrows;
        Hp[i] = (const float4*)(H + (ok[i] ? rr : (nrows - 1)) * D);
    }

    float4 acc[4][8];
#pragma unroll
    for (int i = 0; i < 4; ++i)
#pragma unroll
        for (int j = 0; j < 8; ++j) acc[i][j] = make_float4(0.f, 0.f, 0.f, 0.f);

    for (int k4 = 0; k4 < 32; ++k4) {
        float4 a0 = Hp[0][k4];
        float4 a1 = Hp[1][k4];
        float4 a2 = Hp[2][k4];
        float4 a3 = Hp[3][k4];
        const float* e0 = (const float*)&a0;
        const float* e1 = (const float*)&a1;
        const float* e2 = (const float*)&a2;
        const float* e3 = (const float*)&a3;
#pragma unroll
        for (int kk = 0; kk < 4; ++kk) {
            float s0 = e0[kk], s1 = e1[kk], s2 = e2[kk], s3 = e3[kk];
            int krow = (k4 * 4 + kk) * 32;
#pragma unroll
            for (int jj = 0; jj < 8; ++jj) {
                float4 wv = Wl4[krow + cg + jj * 4];
                acc[0][jj].x += s0 * wv.x; acc[0][jj].y += s0 * wv.y;
                acc[0][jj].z += s0 * wv.z; acc[0][jj].w += s0 * wv.w;
                acc[1][jj].x += s1 * wv.x; acc[1][jj].y += s1 * wv.y;
                acc[1][jj].z += s1 * wv.z; acc[1][jj].w += s1 * wv.w;
                acc[2][jj].x += s2 * wv.x; acc[2][jj].y += s2 * wv.y;
                acc[2][jj].z += s2 * wv.z; acc[2][jj].w += s2 * wv.w;
                acc[3][jj].x += s3 * wv.x; acc[3][jj].y += s3 * wv.y;
                acc[3][jj].z += s3 * wv.z; acc[3][jj].w += s3 * wv.w;
            }
        }
    }

#pragma unroll
    for (int i = 0; i < 4; ++i) {
        if (ok[i]) {
            float4* o = (float4*)(O + (row0 + i) * D);
#pragma unroll
            for (int jj = 0; jj < 8; ++jj) o[cg + jj * 4] = acc[i][jj];
        }
    }
}

// ---------------------------------------------------------------- aggregation (+self+bias [+BN+ReLU])
// one 64-lane wave per node; float2 per lane (512B per edge gather, coalesced).
// R6: 4-edge unroll for MLP depth (was 2); self-row/dinv loads hoisted ahead
// of the edge loop. Probe: latency-bound (pred 133->~100us) vs fabric-bound
// (pred no change).
template <int BN>
__global__ __launch_bounds__(256) void k_agg(const float* __restrict__ HW,
                                             const int* __restrict__ offs,
                                             const int2* __restrict__ csr,
                                             const float* __restrict__ dinv,
                                             const float* __restrict__ bias,
                                             const float* __restrict__ gamma,
                                             const float* __restrict__ beta,
                                             const float* __restrict__ mean,
                                             const float* __restrict__ var,
                                             float* __restrict__ out, int n) {
    int node = blockIdx.x * 4 + (threadIdx.x >> 6);
    if (node >= n) return;
    int lane = threadIdx.x & 63;

    const float2* HW2 = (const float2*)HW;
    // issue independent loads early (overlap with csr chain)
    float2 hv = HW2[(long)node * 64 + lane];
    float dn = dinv[node];
    int s = offs[node], e = offs[node + 1];

    float ax = 0.f, ay = 0.f;
    int j = s;
    for (; j + 3 < e; j += 4) {
        int2 c0 = csr[j];
        int2 c1 = csr[j + 1];
        int2 c2 = csr[j + 2];
        int2 c3 = csr[j + 3];
        float2 r0 = HW2[(long)c0.x * 64 + lane];
        float2 r1 = HW2[(long)c1.x * 64 + lane];
        float2 r2 = HW2[(long)c2.x * 64 + lane];
        float2 r3 = HW2[(long)c3.x * 64 + lane];
        float w0 = __int_as_float(c0.y), w1 = __int_as_float(c1.y);
        float w2 = __int_as_float(c2.y), w3 = __int_as_float(c3.y);
        ax += r0.x * w0; ay += r0.y * w0;
        ax += r1.x * w1; ay += r1.y * w1;
        ax += r2.x * w2; ay += r2.y * w2;
        ax += r3.x * w3; ay += r3.y * w3;
    }
    for (; j < e; ++j) {
        int2 c0 = csr[j];
        float2 r0 = HW2[(long)c0.x * 64 + lane];
        float w0 = __int_as_float(c0.y);
        ax += r0.x * w0; ay += r0.y * w0;
    }

    float sn = dn * dn;
    int c = lane * 2;
    float o0 = ax + hv.x * sn + bias[c];
    float o1 = ay + hv.y * sn + bias[c + 1];
    if (BN) {
        float s0 = gamma[c] * rsqrtf(var[c] + 1e-5f);
        float s1 = gamma[c + 1] * rsqrtf(var[c + 1] + 1e-5f);
        o0 = fmaxf(s0 * (o0 - mean[c]) + beta[c], 0.f);
        o1 = fmaxf(s1 * (o1 - mean[c + 1]) + beta[c + 1], 0.f);
    }
    ((float2*)out)[(long)node * 64 + lane] = make_float2(o0, o1);
}

// ---------------------------------------------------------------- mean pool (batch sorted)
__global__ __launch_bounds__(128) void k_pool(const float* __restrict__ H,
                                              const int* __restrict__ batch,
                                              float* __restrict__ out, int n, int G) {
    int g = blockIdx.x;
    int c = threadIdx.x;  // 128 channels
    int lo = 0, hi = n;
    while (lo < hi) { int m = (lo + hi) >> 1; if (batch[m] < g) lo = m + 1; else hi = m; }
    int s = lo;
    hi = n;
    while (lo < hi) { int m = (lo + hi) >> 1; if (batch[m] < g + 1) lo = m + 1; else hi = m; }
    int e = lo;
    float acc = 0.f;
    for (int r = s; r < e; ++r) acc += H[(long)r * D + c];
    float cnt = (float)(e - s);
    out[(long)g * D + c] = acc / fmaxf(cnt, 1.0f);
}

// ---------------------------------------------------------------- launch

extern "C" void kernel_launch(void* const* d_in, const int* in_sizes, int n_in,
                              void* d_out, int out_size, void* d_ws, size_t ws_size,
                              hipStream_t stream) {
    const float* x     = (const float*)d_in[0];
    const int*   ei    = (const int*)d_in[1];
    const int*   batch = (const int*)d_in[2];
    const float* Ws    = (const float*)d_in[3];
    const float* bs    = (const float*)d_in[4];
    const float* gamma = (const float*)d_in[5];
    const float* beta  = (const float*)d_in[6];
    const float* mean  = (const float*)d_in[7];
    const float* var   = (const float*)d_in[8];

    int n = in_sizes[0] / D;
    int E = in_sizes[1] / 2;
    int G = out_size / D;
    int L = in_sizes[3] / (D * D);
    const int* src = ei;
    const int* dst = ei + E;

    // workspace carve (256B aligned slices)
    char* p = (char*)d_ws;
    auto alloc = [&](size_t bytes) {
        void* r = (void*)p;
        p += (bytes + 255) & ~(size_t)255;
        return r;
    };
    int*   deg    = (int*)alloc((size_t)n * 4);
    int*   offs   = (int*)alloc((size_t)(n + 1) * 4);
    int*   cursor = (int*)alloc((size_t)n * 4);
    float* dinv   = (float*)alloc((size_t)n * 4);
    int nb = (n + 1023) / 1024;
    int*   bsum   = (int*)alloc((size_t)nb * 4);
    int2*  csr    = (int2*)alloc((size_t)E * 8);
    float* bufA   = (float*)alloc((size_t)n * D * 4);
    float* bufB   = (float*)alloc((size_t)n * D * 4);

    hipMemsetAsync(deg, 0, (size_t)n * 4, stream);
    k_count<<<(E + 255) / 256, 256, 0, stream>>>(dst, deg, E);
    k_chunk_sum<<<nb, 256, 0, stream>>>(deg, bsum, n);
    k_scan_bsums<<<1, 64, 0, stream>>>(bsum, nb, offs, n, E);
    k_local_scan<<<nb, 256, 0, stream>>>(deg, bsum, offs, cursor, dinv, n);
    k_fill<<<(E + 255) / 256, 256, 0, stream>>>(src, dst, dinv, cursor, csr, E);

    const float* hin = x;
    for (int l = 0; l < L; ++l) {
        k_gemm<<<(n + 255) / 256, 256, 0, stream>>>(hin, Ws + (size_t)l * D * D, bufB, n);
        if (l < L - 1)
            k_agg<1><<<(n + 3) / 4, 256, 0, stream>>>(bufB, offs, csr, dinv, bs + l * D,
                                                      gamma + l * D, beta + l * D,
                                                      mean + l * D, var + l * D, bufA, n);
        else
            k_agg<0><<<(n + 3) / 4, 256, 0, stream>>>(bufB, offs, csr, dinv, bs + l * D,
                                                      gamma, beta, mean, var, bufA, n);
        hin = bufA;
    }

    k_pool<<<G, 128, 0, stream>>>(bufA, batch, (float*)d_out, n, G);
}

// Round 14
// 1015.605 us; speedup vs baseline: 1.0551x; 1.0551x over previous
//
#include <hip/hip_runtime.h>

#define D 128

// ---------------------------------------------------------------- preprocess

__global__ __launch_bounds__(256) void k_count(const int* __restrict__ dst,
                                               int* __restrict__ deg, int E) {
    int i = blockIdx.x * 256 + threadIdx.x;
    if (i < E) atomicAdd(&deg[dst[i]], 1);
}

// chunk = 1024 elems per block; write per-block sums
__global__ __launch_bounds__(256) void k_chunk_sum(const int* __restrict__ deg,
                                                   int* __restrict__ bsum, int n) {
    __shared__ int sdata[256];
    int base = blockIdx.x * 1024;
    int s = 0;
    for (int j = 0; j < 4; ++j) {
        int idx = base + j * 256 + threadIdx.x;
        if (idx < n) s += deg[idx];
    }
    sdata[threadIdx.x] = s;
    __syncthreads();
    for (int off = 128; off > 0; off >>= 1) {
        if (threadIdx.x < off) sdata[threadIdx.x] += sdata[threadIdx.x + off];
        __syncthreads();
    }
    if (threadIdx.x == 0) bsum[blockIdx.x] = sdata[0];
}

// serial exclusive scan of block sums (nb ~ 98, trivial)
__global__ void k_scan_bsums(int* bsum, int nb, int* offs, int n, int E) {
    if (threadIdx.x == 0 && blockIdx.x == 0) {
        int run = 0;
        for (int i = 0; i < nb; ++i) { int v = bsum[i]; bsum[i] = run; run += v; }
        offs[n] = E;
    }
}

// per-block local exclusive scan + base; also emit cursor copy and dinv
__global__ __launch_bounds__(256) void k_local_scan(const int* __restrict__ deg,
                                                    const int* __restrict__ bsum,
                                                    int* __restrict__ offs,
                                                    int* __restrict__ cursor,
                                                    float* __restrict__ dinv, int n) {
    __shared__ int tsum[256];
    int base = blockIdx.x * 1024;
    int v[4];
    int s = 0;
    for (int j = 0; j < 4; ++j) {
        int idx = base + threadIdx.x * 4 + j;
        v[j] = (idx < n) ? deg[idx] : 0;
        s += v[j];
    }
    tsum[threadIdx.x] = s;
    __syncthreads();
    for (int off = 1; off < 256; off <<= 1) {
        int t = (threadIdx.x >= (unsigned)off) ? tsum[threadIdx.x - off] : 0;
        __syncthreads();
        tsum[threadIdx.x] += t;
        __syncthreads();
    }
    int excl = tsum[threadIdx.x] - s;
    int run = bsum[blockIdx.x] + excl;
    for (int j = 0; j < 4; ++j) {
        int idx = base + threadIdx.x * 4 + j;
        if (idx < n) {
            offs[idx] = run;
            cursor[idx] = run;
            dinv[idx] = rsqrtf((float)v[j] + 1.0f);
            run += v[j];
        }
    }
}

__global__ __launch_bounds__(256) void k_fill(const int* __restrict__ src,
                                              const int* __restrict__ dst,
                                              const float* __restrict__ dinv,
                                              int* __restrict__ cursor,
                                              int2* __restrict__ csr, int E) {
    int i = blockIdx.x * 256 + threadIdx.x;
    if (i >= E) return;
    int s = src[i], d = dst[i];
    int p = atomicAdd(&cursor[d], 1);
    float w = dinv[s] * dinv[d];
    csr[p] = make_int2(s, __float_as_int(w));
}

// ---------------------------------------------------------------- GEMM  H[n,128] @ W[128,128]
// R10 redesign: occupancy, not LDS amortization, is the binding constraint.
// v2 (4 rows/thread, 64KB LDS) = 2 blocks/CU AND ~200 VGPR -> 8 waves/CU
// (2/SIMD): ds_read->FMA stall-bound at ~115us/layer (5x the 21us VALU floor).
// v3: 2 rows/thread (acc 64 VGPR, ~110 total < 128 => 16 waves/CU per m69)
// + W staged in TWO 32KB half-K passes (acc lives in regs across passes)
// -> 4 blocks/CU, 16 waves/CU = 2x wave parallelism for latency hiding.
// Cost: H re-read once (+25MB ~ 7us). Sum order per output unchanged.
// NOTE: no early return -- all threads must reach the mid-kernel barriers.
__global__ __launch_bounds__(256, 4) void k_gemm(const float* __restrict__ H,
                                                 const float* __restrict__ W,
                                                 float* __restrict__ O, int nrows) {
    __shared__ float Wl[64 * 128];          // 32KB: half of W (64 k-rows)
    float4* Wl4 = (float4*)Wl;
    const float4* W4 = (const float4*)W;

    int tr = threadIdx.x >> 2;   // 0..63 -> row pair
    int cg = threadIdx.x & 3;    // col group; cols 4*(cg + 4*jj) .. +3
    long row0 = (long)blockIdx.x * 128 + tr * 2;
    bool ok0 = row0 < nrows;
    bool ok1 = (row0 + 1) < nrows;
    const float4* H0 = (const float4*)(H + (ok0 ? row0 : (nrows - 1)) * D);
    const float4* H1 = (const float4*)(H + (ok1 ? (row0 + 1) : (nrows - 1)) * D);

    float4 acc0[8], acc1[8];
#pragma unroll
    for (int j = 0; j < 8; ++j) {
        acc0[j] = make_float4(0.f, 0.f, 0.f, 0.f);
        acc1[j] = make_float4(0.f, 0.f, 0.f, 0.f);
    }

    for (int pass = 0; pass < 2; ++pass) {
        // stage W[pass*64 .. pass*64+63][:] into LDS (2048 float4)
        if (pass) __syncthreads();          // pass-1 reads done before overwrite
        for (int i = threadIdx.x; i < 2048; i += 256)
            Wl4[i] = W4[pass * 2048 + i];
        __syncthreads();

        for (int k4 = 0; k4 < 16; ++k4) {
            float4 a0 = H0[pass * 16 + k4];
            float4 a1 = H1[pass * 16 + k4];
            const float* e0 = (const float*)&a0;
            const float* e1 = (const float*)&a1;
#pragma unroll
            for (int kk = 0; kk < 4; ++kk) {
                float s0 = e0[kk], s1 = e1[kk];
                int krow = (k4 * 4 + kk) * 32;
#pragma unroll
                for (int jj = 0; jj < 8; ++jj) {
                    float4 wv = Wl4[krow + cg + jj * 4];
                    acc0[jj].x += s0 * wv.x; acc0[jj].y += s0 * wv.y;
                    acc0[jj].z += s0 * wv.z; acc0[jj].w += s0 * wv.w;
                    acc1[jj].x += s1 * wv.x; acc1[jj].y += s1 * wv.y;
                    acc1[jj].z += s1 * wv.z; acc1[jj].w += s1 * wv.w;
                }
            }
        }
    }

    if (ok0) {
        float4* o0 = (float4*)(O + row0 * D);
#pragma unroll
        for (int jj = 0; jj < 8; ++jj) o0[cg + jj * 4] = acc0[jj];
    }
    if (ok1) {
        float4* o1 = (float4*)(O + (row0 + 1) * D);
#pragma unroll
        for (int jj = 0; jj < 8; ++jj) o1[cg + jj * 4] = acc1[jj];
    }
}

// ---------------------------------------------------------------- aggregation (+self+bias [+BN+ReLU])
// one 64-lane wave per node; float2 per lane (512B per edge gather, coalesced).
// R10 verdict: fabric-bound at ~3.7 TB/s L2-miss traffic (4-edge unroll gave
// only -6%); unchanged this round as the control kernel.
template <int BN>
__global__ __launch_bounds__(256) void k_agg(const float* __restrict__ HW,
                                             const int* __restrict__ offs,
                                             const int2* __restrict__ csr,
                                             const float* __restrict__ dinv,
                                             const float* __restrict__ bias,
                                             const float* __restrict__ gamma,
                                             const float* __restrict__ beta,
                                             const float* __restrict__ mean,
                                             const float* __restrict__ var,
                                             float* __restrict__ out, int n) {
    int node = blockIdx.x * 4 + (threadIdx.x >> 6);
    if (node >= n) return;
    int lane = threadIdx.x & 63;

    const float2* HW2 = (const float2*)HW;
    // issue independent loads early (overlap with csr chain)
    float2 hv = HW2[(long)node * 64 + lane];
    float dn = dinv[node];
    int s = offs[node], e = offs[node + 1];

    float ax = 0.f, ay = 0.f;
    int j = s;
    for (; j + 3 < e; j += 4) {
        int2 c0 = csr[j];
        int2 c1 = csr[j + 1];
        int2 c2 = csr[j + 2];
        int2 c3 = csr[j + 3];
        float2 r0 = HW2[(long)c0.x * 64 + lane];
        float2 r1 = HW2[(long)c1.x * 64 + lane];
        float2 r2 = HW2[(long)c2.x * 64 + lane];
        float2 r3 = HW2[(long)c3.x * 64 + lane];
        float w0 = __int_as_float(c0.y), w1 = __int_as_float(c1.y);
        float w2 = __int_as_float(c2.y), w3 = __int_as_float(c3.y);
        ax += r0.x * w0; ay += r0.y * w0;
        ax += r1.x * w1; ay += r1.y * w1;
        ax += r2.x * w2; ay += r2.y * w2;
        ax += r3.x * w3; ay += r3.y * w3;
    }
    for (; j < e; ++j) {
        int2 c0 = csr[j];
        float2 r0 = HW2[(long)c0.x * 64 + lane];
        float w0 = __int_as_float(c0.y);
        ax += r0.x * w0; ay += r0.y * w0;
    }

    float sn = dn * dn;
    int c = lane * 2;
    float o0 = ax + hv.x * sn + bias[c];
    float o1 = ay + hv.y * sn + bias[c + 1];
    if (BN) {
        float s0 = gamma[c] * rsqrtf(var[c] + 1e-5f);
        float s1 = gamma[c + 1] * rsqrtf(var[c + 1] + 1e-5f);
        o0 = fmaxf(s0 * (o0 - mean[c]) + beta[c], 0.f);
        o1 = fmaxf(s1 * (o1 - mean[c + 1]) + beta[c + 1], 0.f);
    }
    ((float2*)out)[(long)node * 64 + lane] = make_float2(o0, o1);
}

// ---------------------------------------------------------------- mean pool (batch sorted)
__global__ __launch_bounds__(128) void k_pool(const float* __restrict__ H,
                                              const int* __restrict__ batch,
                                              float* __restrict__ out, int n, int G) {
    int g = blockIdx.x;
    int c = threadIdx.x;  // 128 channels
    int lo = 0, hi = n;
    while (lo < hi) { int m = (lo + hi) >> 1; if (batch[m] < g) lo = m + 1; else hi = m; }
    int s = lo;
    hi = n;
    while (lo < hi) { int m = (lo + hi) >> 1; if (batch[m] < g + 1) lo = m + 1; else hi = m; }
    int e = lo;
    float acc = 0.f;
    for (int r = s; r < e; ++r) acc += H[(long)r * D + c];
    float cnt = (float)(e - s);
    out[(long)g * D + c] = acc / fmaxf(cnt, 1.0f);
}

// ---------------------------------------------------------------- launch

extern "C" void kernel_launch(void* const* d_in, const int* in_sizes, int n_in,
                              void* d_out, int out_size, void* d_ws, size_t ws_size,
                              hipStream_t stream) {
    const float* x     = (const float*)d_in[0];
    const int*   ei    = (const int*)d_in[1];
    const int*   batch = (const int*)d_in[2];
    const float* Ws    = (const float*)d_in[3];
    const float* bs    = (const float*)d_in[4];
    const float* gamma = (const float*)d_in[5];
    const float* beta  = (const float*)d_in[6];
    const float* mean  = (const float*)d_in[7];
    const float* var   = (const float*)d_in[8];

    int n = in_sizes[0] / D;
    int E = in_sizes[1] / 2;
    int G = out_size / D;
    int L = in_sizes[3] / (D * D);
    const int* src = ei;
    const int* dst = ei + E;

    // workspace carve (256B aligned slices)
    char* p = (char*)d_ws;
    auto alloc = [&](size_t bytes) {
        void* r = (void*)p;
        p += (bytes + 255) & ~(size_t)255;
        return r;
    };
    int*   deg    = (int*)alloc((size_t)n * 4);
    int*   offs   = (int*)alloc((size_t)(n + 1) * 4);
    int*   cursor = (int*)alloc((size_t)n * 4);
    float* dinv   = (float*)alloc((size_t)n * 4);
    int nb = (n + 1023) / 1024;
    int*   bsum   = (int*)alloc((size_t)nb * 4);
    int2*  csr    = (int2*)alloc((size_t)E * 8);
    float* bufA   = (float*)alloc((size_t)n * D * 4);
    float* bufB   = (float*)alloc((size_t)n * D * 4);

    hipMemsetAsync(deg, 0, (size_t)n * 4, stream);
    k_count<<<(E + 255) / 256, 256, 0, stream>>>(dst, deg, E);
    k_chunk_sum<<<nb, 256, 0, stream>>>(deg, bsum, n);
    k_scan_bsums<<<1, 64, 0, stream>>>(bsum, nb, offs, n, E);
    k_local_scan<<<nb, 256, 0, stream>>>(deg, bsum, offs, cursor, dinv, n);
    k_fill<<<(E + 255) / 256, 256, 0, stream>>>(src, dst, dinv, cursor, csr, E);

    const float* hin = x;
    for (int l = 0; l < L; ++l) {
        k_gemm<<<(n + 127) / 128, 256, 0, stream>>>(hin, Ws + (size_t)l * D * D, bufB, n);
        if (l < L - 1)
            k_agg<1><<<(n + 3) / 4, 256, 0, stream>>>(bufB, offs, csr, dinv, bs + l * D,
                                                      gamma + l * D, beta + l * D,
                                                      mean + l * D, var + l * D, bufA, n);
        else
            k_agg<0><<<(n + 3) / 4, 256, 0, stream>>>(bufB, offs, csr, dinv, bs + l * D,
                                                      gamma, beta, mean, var, bufA, n);
        hin = bufA;
    }

    k_pool<<<G, 128, 0, stream>>>(bufA, batch, (float*)d_out, n, G);
}